// Round 10
// baseline (295.017 us; speedup 1.0000x reference)
//
#include <hip/hip_runtime.h>

#define H    128
#define NB   4

typedef __attribute__((ext_vector_type(8))) short short8;
typedef __attribute__((ext_vector_type(4))) float f32x4;

static __device__ __forceinline__ unsigned short f2bf(float f) {
    unsigned u = __float_as_uint(f);
    unsigned r = (u + 0x7fffu + ((u >> 16) & 1u)) >> 16;
    return (unsigned short)r;
}
static __device__ __forceinline__ float bf_lo(unsigned v) {
    return __uint_as_float((v & 0xffffu) << 16);
}
static __device__ __forceinline__ float bf_hi(unsigned v) {
    return __uint_as_float(v & 0xffff0000u);
}
static __device__ __forceinline__ float bfe(short s) {
    return __uint_as_float(((unsigned)(unsigned short)s) << 16);
}

// ------- histogram + per-edge arrival rank -------
__global__ __launch_bounds__(256) void hist_rank(const int* __restrict__ dst,
                                                 int* __restrict__ counts,
                                                 int* __restrict__ rank, int E) {
    int e = blockIdx.x * 256 + threadIdx.x;
    if (e < E) rank[e] = atomicAdd(&counts[dst[e]], 1);
}

// ---------------- hierarchical scan stage 1 ----------------
__global__ __launch_bounds__(1024) void scan_blocks(const int* __restrict__ counts,
                                                    int* __restrict__ partial,
                                                    int* __restrict__ blocksums, int n) {
    __shared__ int buf[1024];
    int tid = threadIdx.x;
    int i = blockIdx.x * 1024 + tid;
    buf[tid] = (i < n) ? counts[i] : 0;
    __syncthreads();
#pragma unroll
    for (int off = 1; off < 1024; off <<= 1) {
        int t = (tid >= off) ? buf[tid - off] : 0;
        __syncthreads();
        buf[tid] += t;
        __syncthreads();
    }
    if (i < n) partial[i] = buf[tid];
    if (tid == 1023) blocksums[blockIdx.x] = buf[1023];
}

// ---------------- stage 2: single-wave scan of block sums (nb <= 64) ----------------
__global__ __launch_bounds__(64) void scan_carry(int* __restrict__ blocksums, int nb) {
    int tid = threadIdx.x;
    int v = (tid < nb) ? blocksums[tid] : 0;
#pragma unroll
    for (int off = 1; off < 64; off <<= 1) {
        int t = __shfl_up(v, off);
        if (tid >= off) v += t;
    }
    if (tid < nb) blocksums[tid] = v;
}

// ---------------- stage 3: add carry, emit offs[0..n] ----------------
__global__ __launch_bounds__(256) void scan_add(const int* __restrict__ partial,
                                                const int* __restrict__ blocksums,
                                                int* __restrict__ offs, int n) {
    int i = blockIdx.x * 256 + threadIdx.x;
    if (i >= n) return;
    int b = i >> 10;
    int carry = (b > 0) ? blocksums[b - 1] : 0;
    offs[i + 1] = partial[i] + carry;
    if (i == 0) offs[0] = 0;
}

// ------- scatter edges into CSR (rank-based); 16B edge records per layer -------
// rec = {src, w[0..1] bf16, w[2..3] bf16, 0} where w = norm*comp[etype]
__global__ __launch_bounds__(256) void scatter_edges(
        const int* __restrict__ src, const int* __restrict__ dst,
        const int* __restrict__ etype, const float* __restrict__ norm,
        const float* __restrict__ comp0, const float* __restrict__ comp1,
        const int* __restrict__ offs, const int* __restrict__ rank,
        uint4* __restrict__ er0, uint4* __restrict__ er1, int E) {
    int e = blockIdx.x * 256 + threadIdx.x;
    if (e >= E) return;
    int pos = offs[dst[e]] + rank[e];
    float w = norm[e];
    int et = etype[e];
    float4 c0 = *(const float4*)(comp0 + et * NB);
    float4 c1 = *(const float4*)(comp1 + et * NB);
    uint4 r0, r1;
    r0.x = (unsigned)src[e];
    r0.y = (unsigned)f2bf(w * c0.x) | ((unsigned)f2bf(w * c0.y) << 16);
    r0.z = (unsigned)f2bf(w * c0.z) | ((unsigned)f2bf(w * c0.w) << 16);
    r0.w = 0;
    r1.x = (unsigned)src[e];
    r1.y = (unsigned)f2bf(w * c1.x) | ((unsigned)f2bf(w * c1.y) << 16);
    r1.z = (unsigned)f2bf(w * c1.z) | ((unsigned)f2bf(w * c1.w) << 16);
    r1.w = 0;
    er0[pos] = r0;
    er1[pos] = r1;
}

// ---------------- f32 -> bf16 convert ----------------
__global__ __launch_bounds__(256) void convert_bf16(const float* __restrict__ in,
                                                    unsigned short* __restrict__ out, int n4) {
    int i = blockIdx.x * 256 + threadIdx.x;
    if (i >= n4) return;
    float4 v = ((const float4*)in)[i];
    ushort4 o;
    o.x = f2bf(v.x); o.y = f2bf(v.y); o.z = f2bf(v.z); o.w = f2bf(v.w);
    ((ushort4*)out)[i] = o;
}

// ---- Wb build: Wb[l][o][b*128+d] = bf16(basis_l[b][d][o])  (pure transpose) ----
__global__ __launch_bounds__(128) void make_wb(
        const float* __restrict__ basis0, const float* __restrict__ basis1,
        unsigned short* __restrict__ Wb) {
    int b = blockIdx.x;        // 0..3
    int d = blockIdx.y;        // 0..127
    int l = blockIdx.z;        // 0..1
    int o = threadIdx.x;       // 0..127
    const float* basis = l ? basis1 : basis0;
    float s = basis[((size_t)b * H + d) * H + o];
    Wb[((size_t)l * H + o) * (NB * H) + b * H + d] = f2bf(s);
}

// ---------------- aggregation: per-basis weighted sum of gathered rows ----------------
// 256 threads = 16 nodes x 16 chans. No LDS, no barrier -> full occupancy.
// Output: agg[v][b*128 + c] bf16 (basis-major K=512 row per node).
#define EACC(REC, HV) {                                                 \
    float wa = bf_lo(REC.y), wb = bf_hi(REC.y);                         \
    float wc = bf_lo(REC.z), wd = bf_hi(REC.z);                         \
    _Pragma("unroll")                                                   \
    for (int c = 0; c < 8; ++c) {                                       \
        float f = bfe(HV[c]);                                           \
        a0[c] = fmaf(wa, f, a0[c]); a1[c] = fmaf(wb, f, a1[c]);         \
        a2[c] = fmaf(wc, f, a2[c]); a3[c] = fmaf(wd, f, a3[c]);         \
    } }

__global__ __launch_bounds__(256, 8) void agg_nodes(
        const unsigned short* __restrict__ hin,   // [M][128] bf16
        const int* __restrict__ offs,             // [M+1]
        const uint4* __restrict__ er,             // 16B edge records (this layer)
        unsigned short* __restrict__ agg,         // [M][512] bf16
        int M) {
    const int tid = threadIdx.x;
    const int nl  = tid >> 4;      // local node 0..15
    const int ch  = tid & 15;      // 16B chunk of the 256B source row
    const int v   = blockIdx.x * 16 + nl;
    if (v >= M) return;

    float a0[8], a1[8], a2[8], a3[8];
#pragma unroll
    for (int c = 0; c < 8; ++c) { a0[c] = 0.f; a1[c] = 0.f; a2[c] = 0.f; a3[c] = 0.f; }

    const int beg = offs[v], end = offs[v + 1];
    int e = beg;
    for (; e + 2 <= end; e += 2) {
        uint4 r0 = er[e];
        uint4 r1 = er[e + 1];
        short8 h0 = *(const short8*)(hin + (size_t)r0.x * H + ch * 8);
        short8 h1 = *(const short8*)(hin + (size_t)r1.x * H + ch * 8);
        EACC(r0, h0)
        EACC(r1, h1)
    }
    if (e < end) {
        uint4 r0 = er[e];
        short8 h0 = *(const short8*)(hin + (size_t)r0.x * H + ch * 8);
        EACC(r0, h0)
    }

    unsigned short* orow = agg + (size_t)v * (NB * H) + ch * 8;
    uint4 pk;
#define PACK(A) pk.x = (unsigned)f2bf(A[0]) | ((unsigned)f2bf(A[1]) << 16); \
                pk.y = (unsigned)f2bf(A[2]) | ((unsigned)f2bf(A[3]) << 16); \
                pk.z = (unsigned)f2bf(A[4]) | ((unsigned)f2bf(A[5]) << 16); \
                pk.w = (unsigned)f2bf(A[6]) | ((unsigned)f2bf(A[7]) << 16);
    PACK(a0) *(uint4*)(orow + 0 * H) = pk;
    PACK(a1) *(uint4*)(orow + 1 * H) = pk;
    PACK(a2) *(uint4*)(orow + 2 * H) = pk;
    PACK(a3) *(uint4*)(orow + 3 * H) = pk;
#undef PACK
}

// ---------------- output GEMM: out[32 rows] = agg[32][512] @ Wb[512][128] ----------------
// block 512 (8 waves); wave w -> cols [w*16, w*16+16). A-frags read straight from
// global (16B/lane, rows shared by all 8 waves -> L1); B rows L2-resident.
__global__ __launch_bounds__(512) void gemm_out(
        const unsigned short* __restrict__ agg,   // [M][512] bf16
        const unsigned short* __restrict__ Wb,    // [128 o][512 k] bf16
        const float* __restrict__ bias,
        void* __restrict__ outp, int M, int write_bf16) {
    const int tid  = threadIdx.x;
    const int wid  = tid >> 6;
    const int lane = tid & 63;
    const int v0   = blockIdx.x * 32;
    const int n0   = wid * 16;
    const int lr   = lane & 15;
    const int lg   = lane >> 4;

    const int ar0 = min(v0 + lr, M - 1);
    const int ar1 = min(v0 + 16 + lr, M - 1);
    const char* bbase  = (const char*)Wb + (size_t)(n0 + lr) * (NB * H) * 2;
    const char* a0base = (const char*)(agg + (size_t)ar0 * (NB * H));
    const char* a1base = (const char*)(agg + (size_t)ar1 * (NB * H));

    f32x4 acc0 = (f32x4){0.f, 0.f, 0.f, 0.f};
    f32x4 acc1 = (f32x4){0.f, 0.f, 0.f, 0.f};
#pragma unroll
    for (int ks = 0; ks < 16; ++ks) {
        const int kb = ks * 64 + lg * 16;
        short8 b   = *(const short8*)(bbase + kb);
        short8 av0 = *(const short8*)(a0base + kb);
        short8 av1 = *(const short8*)(a1base + kb);
        acc0 = __builtin_amdgcn_mfma_f32_16x16x32_bf16(av0, b, acc0, 0, 0, 0);
        acc1 = __builtin_amdgcn_mfma_f32_16x16x32_bf16(av1, b, acc1, 0, 0, 0);
    }

    const float bcol = bias[n0 + lr];
#pragma unroll
    for (int m = 0; m < 2; ++m) {
        const f32x4 a = m ? acc1 : acc0;
#pragma unroll
        for (int j = 0; j < 4; ++j) {
            const int rl   = m * 16 + lg * 4 + j;
            const int grow = v0 + rl;
            if (grow < M) {
                float val = fmaxf(a[j] + bcol, 0.f);
                if (write_bf16)
                    ((unsigned short*)outp)[(size_t)grow * H + n0 + lr] = f2bf(val);
                else
                    ((float*)outp)[(size_t)grow * H + n0 + lr] = val;
            }
        }
    }
}

extern "C" void kernel_launch(void* const* d_in, const int* in_sizes, int n_in,
                              void* d_out, int out_size, void* d_ws, size_t ws_size,
                              hipStream_t stream) {
    const float* feats  = (const float*)d_in[0];
    const int*   src    = (const int*)  d_in[1];
    const int*   dst    = (const int*)  d_in[2];
    const int*   etype  = (const int*)  d_in[3];
    const float* norm   = (const float*)d_in[4];
    const float* basis0 = (const float*)d_in[5];
    const float* comp0  = (const float*)d_in[6];
    const float* bias0  = (const float*)d_in[7];
    const float* basis1 = (const float*)d_in[8];
    const float* comp1  = (const float*)d_in[9];
    const float* bias1  = (const float*)d_in[10];
    float* out = (float*)d_out;

    const int M = in_sizes[0] / H;     // 50000
    const int E = in_sizes[1];         // 600000

    // workspace carve-up (256B aligned)
    char* ws = (char*)d_ws;
    size_t cur = 0;
    auto take = [&](size_t bytes) { void* p = ws + cur; cur += (bytes + 255) & ~(size_t)255; return p; };
    unsigned short* hbf  = (unsigned short*)take((size_t)M * H * 2);           // 12.8 MB
    unsigned short* h1bf = (unsigned short*)take((size_t)M * H * 2);           // 12.8 MB
    unsigned short* agg  = (unsigned short*)take((size_t)M * NB * H * 2);      // 51.2 MB
    unsigned short* Wb   = (unsigned short*)take((size_t)2 * H * NB * H * 2);  // 256 KB
    int*   counts  = (int*)take((size_t)M * 4);
    int*   offs    = (int*)take((size_t)(M + 1) * 4);
    int*   partial = (int*)take((size_t)M * 4);
    int*   bsums   = (int*)take((size_t)64 * 4);
    int*   rank    = (int*)take((size_t)E * 4);
    uint4* er0     = (uint4*)take((size_t)E * 16);                             // 9.6 MB
    uint4* er1     = (uint4*)take((size_t)E * 16);                             // 9.6 MB

    dim3 blk(256);
    int eb  = (E + 255) / 256;
    int n4  = M * H / 4;
    int cb  = (n4 + 255) / 256;
    int mb  = (M + 255) / 256;
    int nsb = (M + 1023) / 1024;         // 49 <= 64
    int ab  = (M + 15) / 16;             // 3125 agg blocks
    int gb  = (M + 31) / 32;             // 1563 gemm blocks

    // ---- graph prep (stateless every call, single CSR build) ----
    hipMemsetAsync(counts, 0, (size_t)M * 4, stream);
    hist_rank    <<<eb, blk, 0, stream>>>(dst, counts, rank, E);
    scan_blocks  <<<nsb, 1024, 0, stream>>>(counts, partial, bsums, M);
    scan_carry   <<<1, 64, 0, stream>>>(bsums, nsb);
    scan_add     <<<mb, blk, 0, stream>>>(partial, bsums, offs, M);
    scatter_edges<<<eb, blk, 0, stream>>>(src, dst, etype, norm, comp0, comp1,
                                          offs, rank, er0, er1, E);
    convert_bf16 <<<cb, blk, 0, stream>>>(feats, hbf, n4);
    make_wb      <<<dim3(NB, H, 2), 128, 0, stream>>>(basis0, basis1, Wb);

    // ---- layer 0 ----
    agg_nodes<<<ab, blk, 0, stream>>>(hbf, offs, er0, agg, M);
    gemm_out <<<gb, 512, 0, stream>>>(agg, Wb, bias0, h1bf, M, 1);
    // ---- layer 1 ----
    agg_nodes<<<ab, blk, 0, stream>>>(h1bf, offs, er1, agg, M);
    gemm_out <<<gb, 512, 0, stream>>>(agg, Wb + (size_t)H * NB * H, bias1, out, M, 0);
}

// Round 11
// 221.345 us; speedup vs baseline: 1.3328x; 1.3328x over previous
//
#include <hip/hip_runtime.h>

#define H    128
#define NB   4

typedef __attribute__((ext_vector_type(8))) short short8;
typedef __attribute__((ext_vector_type(4))) float f32x4;

static __device__ __forceinline__ unsigned short f2bf(float f) {
    unsigned u = __float_as_uint(f);
    unsigned r = (u + 0x7fffu + ((u >> 16) & 1u)) >> 16;
    return (unsigned short)r;
}
static __device__ __forceinline__ float bfe(short s) {
    return __uint_as_float(((unsigned)(unsigned short)s) << 16);
}

// ------- histogram + per-edge arrival rank -------
__global__ __launch_bounds__(256) void hist_rank(const int* __restrict__ dst,
                                                 int* __restrict__ counts,
                                                 int* __restrict__ rank, int E) {
    int e = blockIdx.x * 256 + threadIdx.x;
    if (e < E) rank[e] = atomicAdd(&counts[dst[e]], 1);
}

// ---------------- hierarchical scan stage 1 ----------------
__global__ __launch_bounds__(1024) void scan_blocks(const int* __restrict__ counts,
                                                    int* __restrict__ partial,
                                                    int* __restrict__ blocksums, int n) {
    __shared__ int buf[1024];
    int tid = threadIdx.x;
    int i = blockIdx.x * 1024 + tid;
    buf[tid] = (i < n) ? counts[i] : 0;
    __syncthreads();
#pragma unroll
    for (int off = 1; off < 1024; off <<= 1) {
        int t = (tid >= off) ? buf[tid - off] : 0;
        __syncthreads();
        buf[tid] += t;
        __syncthreads();
    }
    if (i < n) partial[i] = buf[tid];
    if (tid == 1023) blocksums[blockIdx.x] = buf[1023];
}

// ---------------- stage 2: single-wave scan of block sums (nb <= 64) ----------------
__global__ __launch_bounds__(64) void scan_carry(int* __restrict__ blocksums, int nb) {
    int tid = threadIdx.x;
    int v = (tid < nb) ? blocksums[tid] : 0;
#pragma unroll
    for (int off = 1; off < 64; off <<= 1) {
        int t = __shfl_up(v, off);
        if (tid >= off) v += t;
    }
    if (tid < nb) blocksums[tid] = v;
}

// ---------------- stage 3: add carry, emit offs[0..n] ----------------
__global__ __launch_bounds__(256) void scan_add(const int* __restrict__ partial,
                                                const int* __restrict__ blocksums,
                                                int* __restrict__ offs, int n) {
    int i = blockIdx.x * 256 + threadIdx.x;
    if (i >= n) return;
    int b = i >> 10;
    int carry = (b > 0) ? blocksums[b - 1] : 0;
    offs[i + 1] = partial[i] + carry;
    if (i == 0) offs[0] = 0;
}

// ------- scatter edges into CSR (rank-based); 8B record shared by both layers -------
// rec = { src | etype<<17, norm }
__global__ __launch_bounds__(256) void scatter_edges(
        const int* __restrict__ src, const int* __restrict__ dst,
        const int* __restrict__ etype, const float* __restrict__ norm,
        const int* __restrict__ offs, const int* __restrict__ rank,
        uint2* __restrict__ er, int E) {
    int e = blockIdx.x * 256 + threadIdx.x;
    if (e >= E) return;
    int pos = offs[dst[e]] + rank[e];
    uint2 r;
    r.x = (unsigned)src[e] | ((unsigned)etype[e] << 17);
    r.y = __float_as_uint(norm[e]);
    er[pos] = r;
}

// ---------------- f32 -> bf16 convert ----------------
__global__ __launch_bounds__(256) void convert_bf16(const float* __restrict__ in,
                                                    unsigned short* __restrict__ out, int n4) {
    int i = blockIdx.x * 256 + threadIdx.x;
    if (i >= n4) return;
    float4 v = ((const float4*)in)[i];
    ushort4 o;
    o.x = f2bf(v.x); o.y = f2bf(v.y); o.z = f2bf(v.z); o.w = f2bf(v.w);
    ((ushort4*)out)[i] = o;
}

// ---- Wb build: Wb[l][o][b*128+d] = bf16(basis_l[b][d][o])  (pure transpose) ----
__global__ __launch_bounds__(128) void make_wb(
        const float* __restrict__ basis0, const float* __restrict__ basis1,
        unsigned short* __restrict__ Wb) {
    int b = blockIdx.x;        // 0..3
    int d = blockIdx.y;        // 0..127
    int l = blockIdx.z;        // 0..1
    int o = threadIdx.x;       // 0..127
    const float* basis = l ? basis1 : basis0;
    float s = basis[((size_t)b * H + d) * H + o];
    Wb[((size_t)l * H + o) * (NB * H) + b * H + d] = f2bf(s);
}

// ---------------- aggregation: per-basis weighted sum of gathered rows ----------------
// 256 threads = 16 nodes x 16 chans. comp table in LDS (128B), no other LDS use.
// Output: agg[v][b*128 + c] bf16 (basis-major K=512 row per node).
#define EACC(WA, WB, WC, WD, HV) {                                      \
    _Pragma("unroll")                                                   \
    for (int c = 0; c < 8; ++c) {                                       \
        float f = bfe(HV[c]);                                           \
        a0[c] = fmaf(WA, f, a0[c]); a1[c] = fmaf(WB, f, a1[c]);         \
        a2[c] = fmaf(WC, f, a2[c]); a3[c] = fmaf(WD, f, a3[c]);         \
    } }

__global__ __launch_bounds__(256, 8) void agg_nodes(
        const unsigned short* __restrict__ hin,   // [M][128] bf16
        const int* __restrict__ offs,             // [M+1]
        const uint2* __restrict__ er,             // 8B edge records (shared)
        const float* __restrict__ comp,           // [8][4] f32, this layer
        unsigned short* __restrict__ agg,         // [M][512] bf16
        int M) {
    __shared__ float cmp[32];
    const int tid = threadIdx.x;
    if (tid < 32) cmp[tid] = comp[tid];
    __syncthreads();

    const int nl  = tid >> 4;      // local node 0..15
    const int ch  = tid & 15;      // 16B chunk of the 256B source row
    const int v   = blockIdx.x * 16 + nl;
    if (v >= M) return;

    float a0[8], a1[8], a2[8], a3[8];
#pragma unroll
    for (int c = 0; c < 8; ++c) { a0[c] = 0.f; a1[c] = 0.f; a2[c] = 0.f; a3[c] = 0.f; }

    const int beg = offs[v], end = offs[v + 1];
    int e = beg;
    for (; e + 2 <= end; e += 2) {
        uint2 r0 = er[e];
        uint2 r1 = er[e + 1];
        short8 h0 = *(const short8*)(hin + (size_t)(r0.x & 0x1FFFF) * H + ch * 8);
        short8 h1 = *(const short8*)(hin + (size_t)(r1.x & 0x1FFFF) * H + ch * 8);
        {
            const float* c0 = cmp + (r0.x >> 17) * 4;
            float w = __uint_as_float(r0.y);
            float wa = w * c0[0], wb = w * c0[1], wc = w * c0[2], wd = w * c0[3];
            EACC(wa, wb, wc, wd, h0)
        }
        {
            const float* c1 = cmp + (r1.x >> 17) * 4;
            float w = __uint_as_float(r1.y);
            float wa = w * c1[0], wb = w * c1[1], wc = w * c1[2], wd = w * c1[3];
            EACC(wa, wb, wc, wd, h1)
        }
    }
    if (e < end) {
        uint2 r0 = er[e];
        short8 h0 = *(const short8*)(hin + (size_t)(r0.x & 0x1FFFF) * H + ch * 8);
        const float* c0 = cmp + (r0.x >> 17) * 4;
        float w = __uint_as_float(r0.y);
        float wa = w * c0[0], wb = w * c0[1], wc = w * c0[2], wd = w * c0[3];
        EACC(wa, wb, wc, wd, h0)
    }

    unsigned short* orow = agg + (size_t)v * (NB * H) + ch * 8;
    uint4 pk;
#define PACK(A) pk.x = (unsigned)f2bf(A[0]) | ((unsigned)f2bf(A[1]) << 16); \
                pk.y = (unsigned)f2bf(A[2]) | ((unsigned)f2bf(A[3]) << 16); \
                pk.z = (unsigned)f2bf(A[4]) | ((unsigned)f2bf(A[5]) << 16); \
                pk.w = (unsigned)f2bf(A[6]) | ((unsigned)f2bf(A[7]) << 16);
    PACK(a0) *(uint4*)(orow + 0 * H) = pk;
    PACK(a1) *(uint4*)(orow + 1 * H) = pk;
    PACK(a2) *(uint4*)(orow + 2 * H) = pk;
    PACK(a3) *(uint4*)(orow + 3 * H) = pk;
#undef PACK
}

// ---------------- output GEMM: out[32 rows] = agg[32][512] @ Wb[512][128] ----------------
// block 512 (8 waves). A-tile staged coalesced -> swizzled LDS; fragments via
// ds_read_b128 (R7's proven phase B). B from global (L2-resident).
__global__ __launch_bounds__(512) void gemm_out(
        const unsigned short* __restrict__ agg,   // [M][512] bf16
        const unsigned short* __restrict__ Wb,    // [128 o][512 k] bf16
        const float* __restrict__ bias,
        void* __restrict__ outp, int M, int write_bf16) {
    __shared__ char lds[32 * 1024];               // A tile: 32 rows x 1024 B
    const int tid  = threadIdx.x;
    const int v0   = blockIdx.x * 32;

    // stage A tile (coalesced 16B per thread x 4)
#pragma unroll
    for (int i = 0; i < 4; ++i) {
        int id  = tid + i * 512;       // 0..2047
        int row = id >> 6;             // 0..31
        int c16 = id & 63;             // 16B chunk within 1024B row
        int gr  = min(v0 + row, M - 1);
        uint4 vld = *(const uint4*)((const char*)agg + (size_t)gr * 1024 + c16 * 16);
        *(uint4*)(lds + row * 1024 + ((c16 * 16) ^ ((row & 7) << 4))) = vld;
    }
    __syncthreads();

    const int wid  = tid >> 6;
    const int lane = tid & 63;
    const int n0 = wid * 16;           // this wave's 16 output cols
    const int lr = lane & 15;
    const int lg = lane >> 4;
    const char* bbase = (const char*)Wb + (size_t)(n0 + lr) * (NB * H) * 2;
    const int swz = (lr & 7) << 4;

    f32x4 acc0 = (f32x4){0.f, 0.f, 0.f, 0.f};
    f32x4 acc1 = (f32x4){0.f, 0.f, 0.f, 0.f};
#pragma unroll
    for (int ks = 0; ks < 16; ++ks) {
        const int kb = ks * 64 + lg * 16;
        short8 b   = *(const short8*)(bbase + kb);
        short8 av0 = *(const short8*)(lds + (lr)      * 1024 + (kb ^ swz));
        short8 av1 = *(const short8*)(lds + (16 + lr) * 1024 + (kb ^ swz));
        acc0 = __builtin_amdgcn_mfma_f32_16x16x32_bf16(av0, b, acc0, 0, 0, 0);
        acc1 = __builtin_amdgcn_mfma_f32_16x16x32_bf16(av1, b, acc1, 0, 0, 0);
    }

    const float bcol = bias[n0 + lr];
#pragma unroll
    for (int m = 0; m < 2; ++m) {
        const f32x4 a = m ? acc1 : acc0;
#pragma unroll
        for (int j = 0; j < 4; ++j) {
            const int rl   = m * 16 + lg * 4 + j;
            const int grow = v0 + rl;
            if (grow < M) {
                float val = fmaxf(a[j] + bcol, 0.f);
                if (write_bf16)
                    ((unsigned short*)outp)[(size_t)grow * H + n0 + lr] = f2bf(val);
                else
                    ((float*)outp)[(size_t)grow * H + n0 + lr] = val;
            }
        }
    }
}

extern "C" void kernel_launch(void* const* d_in, const int* in_sizes, int n_in,
                              void* d_out, int out_size, void* d_ws, size_t ws_size,
                              hipStream_t stream) {
    const float* feats  = (const float*)d_in[0];
    const int*   src    = (const int*)  d_in[1];
    const int*   dst    = (const int*)  d_in[2];
    const int*   etype  = (const int*)  d_in[3];
    const float* norm   = (const float*)d_in[4];
    const float* basis0 = (const float*)d_in[5];
    const float* comp0  = (const float*)d_in[6];
    const float* bias0  = (const float*)d_in[7];
    const float* basis1 = (const float*)d_in[8];
    const float* comp1  = (const float*)d_in[9];
    const float* bias1  = (const float*)d_in[10];
    float* out = (float*)d_out;

    const int M = in_sizes[0] / H;     // 50000
    const int E = in_sizes[1];         // 600000

    // workspace carve-up (256B aligned)
    char* ws = (char*)d_ws;
    size_t cur = 0;
    auto take = [&](size_t bytes) { void* p = ws + cur; cur += (bytes + 255) & ~(size_t)255; return p; };
    unsigned short* hbf  = (unsigned short*)take((size_t)M * H * 2);           // 12.8 MB
    unsigned short* h1bf = (unsigned short*)take((size_t)M * H * 2);           // 12.8 MB
    unsigned short* agg  = (unsigned short*)take((size_t)M * NB * H * 2);      // 51.2 MB
    unsigned short* Wb   = (unsigned short*)take((size_t)2 * H * NB * H * 2);  // 256 KB
    int*   counts  = (int*)take((size_t)M * 4);
    int*   offs    = (int*)take((size_t)(M + 1) * 4);
    int*   partial = (int*)take((size_t)M * 4);
    int*   bsums   = (int*)take((size_t)64 * 4);
    int*   rank    = (int*)take((size_t)E * 4);
    uint2* er      = (uint2*)take((size_t)E * 8);                              // 4.8 MB

    dim3 blk(256);
    int eb  = (E + 255) / 256;
    int n4  = M * H / 4;
    int cb  = (n4 + 255) / 256;
    int mb  = (M + 255) / 256;
    int nsb = (M + 1023) / 1024;         // 49 <= 64
    int ab  = (M + 15) / 16;             // 3125 agg blocks
    int gb  = (M + 31) / 32;             // 1563 gemm blocks

    // ---- graph prep (stateless every call, single CSR build) ----
    hipMemsetAsync(counts, 0, (size_t)M * 4, stream);
    hist_rank    <<<eb, blk, 0, stream>>>(dst, counts, rank, E);
    scan_blocks  <<<nsb, 1024, 0, stream>>>(counts, partial, bsums, M);
    scan_carry   <<<1, 64, 0, stream>>>(bsums, nsb);
    scan_add     <<<mb, blk, 0, stream>>>(partial, bsums, offs, M);
    scatter_edges<<<eb, blk, 0, stream>>>(src, dst, etype, norm, offs, rank, er, E);
    convert_bf16 <<<cb, blk, 0, stream>>>(feats, hbf, n4);
    make_wb      <<<dim3(NB, H, 2), 128, 0, stream>>>(basis0, basis1, Wb);

    // ---- layer 0 ----
    agg_nodes<<<ab, blk, 0, stream>>>(hbf, offs, er, comp0, agg, M);
    gemm_out <<<gb, 512, 0, stream>>>(agg, Wb, bias0, h1bf, M, 1);
    // ---- layer 1 ----
    agg_nodes<<<ab, blk, 0, stream>>>(h1bf, offs, er, comp1, agg, M);
    gemm_out <<<gb, 512, 0, stream>>>(agg, Wb + (size_t)H * NB * H, bias1, out, M, 0);
}

// Round 12
// 194.600 us; speedup vs baseline: 1.5160x; 1.1374x over previous
//
#include <hip/hip_runtime.h>

#define H    128
#define NB   4
#define DT   32    // dst-nodes per block in fused kernel

typedef __attribute__((ext_vector_type(8))) short short8;
typedef __attribute__((ext_vector_type(4))) float f32x4;

static __device__ __forceinline__ unsigned short f2bf(float f) {
    unsigned u = __float_as_uint(f);
    unsigned r = (u + 0x7fffu + ((u >> 16) & 1u)) >> 16;
    return (unsigned short)r;
}
static __device__ __forceinline__ float bfe(short s) {
    return __uint_as_float(((unsigned)(unsigned short)s) << 16);
}

// ------- histogram + per-edge arrival rank -------
__global__ __launch_bounds__(256) void hist_rank(const int* __restrict__ dst,
                                                 int* __restrict__ counts,
                                                 int* __restrict__ rank, int E) {
    int e = blockIdx.x * 256 + threadIdx.x;
    if (e < E) rank[e] = atomicAdd(&counts[dst[e]], 1);
}

// ---------------- hierarchical scan stage 1 ----------------
__global__ __launch_bounds__(1024) void scan_blocks(const int* __restrict__ counts,
                                                    int* __restrict__ partial,
                                                    int* __restrict__ blocksums, int n) {
    __shared__ int buf[1024];
    int tid = threadIdx.x;
    int i = blockIdx.x * 1024 + tid;
    buf[tid] = (i < n) ? counts[i] : 0;
    __syncthreads();
#pragma unroll
    for (int off = 1; off < 1024; off <<= 1) {
        int t = (tid >= off) ? buf[tid - off] : 0;
        __syncthreads();
        buf[tid] += t;
        __syncthreads();
    }
    if (i < n) partial[i] = buf[tid];
    if (tid == 1023) blocksums[blockIdx.x] = buf[1023];
}

// ---------------- stage 2: single-wave scan of block sums (nb <= 64) ----------------
__global__ __launch_bounds__(64) void scan_carry(int* __restrict__ blocksums, int nb) {
    int tid = threadIdx.x;
    int v = (tid < nb) ? blocksums[tid] : 0;
#pragma unroll
    for (int off = 1; off < 64; off <<= 1) {
        int t = __shfl_up(v, off);
        if (tid >= off) v += t;
    }
    if (tid < nb) blocksums[tid] = v;
}

// ---------------- stage 3: add carry, emit offs[0..n] ----------------
__global__ __launch_bounds__(256) void scan_add(const int* __restrict__ partial,
                                                const int* __restrict__ blocksums,
                                                int* __restrict__ offs, int n) {
    int i = blockIdx.x * 256 + threadIdx.x;
    if (i >= n) return;
    int b = i >> 10;
    int carry = (b > 0) ? blocksums[b - 1] : 0;
    offs[i + 1] = partial[i] + carry;
    if (i == 0) offs[0] = 0;
}

// ------- scatter edges into CSR (rank-based); 8B record shared by both layers -------
// rec = { src | etype<<17, norm }
__global__ __launch_bounds__(256) void scatter_edges(
        const int* __restrict__ src, const int* __restrict__ dst,
        const int* __restrict__ etype, const float* __restrict__ norm,
        const int* __restrict__ offs, const int* __restrict__ rank,
        uint2* __restrict__ er, int E) {
    int e = blockIdx.x * 256 + threadIdx.x;
    if (e >= E) return;
    int pos = offs[dst[e]] + rank[e];
    uint2 r;
    r.x = (unsigned)src[e] | ((unsigned)etype[e] << 17);
    r.y = __float_as_uint(norm[e]);
    er[pos] = r;
}

// ---------------- f32 -> bf16 convert ----------------
__global__ __launch_bounds__(256) void convert_bf16(const float* __restrict__ in,
                                                    unsigned short* __restrict__ out, int n4) {
    int i = blockIdx.x * 256 + threadIdx.x;
    if (i >= n4) return;
    float4 v = ((const float4*)in)[i];
    ushort4 o;
    o.x = f2bf(v.x); o.y = f2bf(v.y); o.z = f2bf(v.z); o.w = f2bf(v.w);
    ((ushort4*)out)[i] = o;
}

// ---- Wb build: Wb[l][o][b*128+d] = bf16(basis_l[b][d][o])  (pure transpose) ----
__global__ __launch_bounds__(128) void make_wb(
        const float* __restrict__ basis0, const float* __restrict__ basis1,
        unsigned short* __restrict__ Wb) {
    int b = blockIdx.x;        // 0..3
    int d = blockIdx.y;        // 0..127
    int l = blockIdx.z;        // 0..1
    int o = threadIdx.x;       // 0..127
    const float* basis = l ? basis1 : basis0;
    float s = basis[((size_t)b * H + d) * H + o];
    Wb[((size_t)l * H + o) * (NB * H) + b * H + d] = f2bf(s);
}

// ---------------- fused layer: basis-agg (LDS) + MFMA GEMM + bias + relu ----------------
// block = 512 threads (8 waves), DT=32 dst nodes, K = NB*H = 512.
// Phase A: thread = (node nl = tid>>4, chunk ch = tid&15). Unroll-4: 4 independent
//          8B rec loads + 4 independent 16B row gathers in flight; weights from
//          LDS comp table; 32 private f32 accumulators.
// Phase B: wave w computes output cols [w*16, w*16+16) for all 32 rows (R7 proven).
#define EACC(R, HV) {                                                   \
    const float* cp = cmp + ((R.x >> 17) & 7) * 4;                      \
    float w = __uint_as_float(R.y);                                     \
    float wa = w * cp[0], wb = w * cp[1];                               \
    float wc = w * cp[2], wd = w * cp[3];                               \
    _Pragma("unroll")                                                   \
    for (int c = 0; c < 8; ++c) {                                       \
        float f = bfe(HV[c]);                                           \
        a0[c] = fmaf(wa, f, a0[c]); a1[c] = fmaf(wb, f, a1[c]);         \
        a2[c] = fmaf(wc, f, a2[c]); a3[c] = fmaf(wd, f, a3[c]);         \
    } }

__global__ __launch_bounds__(512, 4) void fused_layer(
        const unsigned short* __restrict__ hin,   // [M][128] bf16
        const int* __restrict__ offs,             // [M+1]
        const uint2* __restrict__ er,             // 8B edge records (shared)
        const float* __restrict__ comp,           // [8][4] f32, this layer
        const unsigned short* __restrict__ Wb,    // [128 o][512 k] bf16
        const float* __restrict__ bias,
        void* __restrict__ outp, int M, int write_bf16) {
    __shared__ char lds[DT * 1024];               // 32 KB: AggTile[32][512] bf16
    __shared__ float cmp[32];
    const int tid  = threadIdx.x;
    if (tid < 32) cmp[tid] = comp[tid];
    __syncthreads();

    const int nl   = tid >> 4;     // local node 0..31
    const int ch   = tid & 15;     // 16B chunk of the 256B row
    const int v0   = blockIdx.x * DT;
    const int v    = v0 + nl;

    // ---------------- phase A: private per-thread aggregation, unroll-4 ----------------
    float a0[8], a1[8], a2[8], a3[8];
#pragma unroll
    for (int c = 0; c < 8; ++c) { a0[c] = 0.f; a1[c] = 0.f; a2[c] = 0.f; a3[c] = 0.f; }

    if (v < M) {
        const int beg = offs[v], end = offs[v + 1];
        int e = beg;
        for (; e + 4 <= end; e += 4) {
            uint2 r0 = er[e];
            uint2 r1 = er[e + 1];
            uint2 r2 = er[e + 2];
            uint2 r3 = er[e + 3];
            short8 h0 = *(const short8*)(hin + (size_t)(r0.x & 0x1FFFF) * H + ch * 8);
            short8 h1 = *(const short8*)(hin + (size_t)(r1.x & 0x1FFFF) * H + ch * 8);
            short8 h2 = *(const short8*)(hin + (size_t)(r2.x & 0x1FFFF) * H + ch * 8);
            short8 h3 = *(const short8*)(hin + (size_t)(r3.x & 0x1FFFF) * H + ch * 8);
            EACC(r0, h0) EACC(r1, h1) EACC(r2, h2) EACC(r3, h3)
        }
        for (; e < end; ++e) {
            uint2 r0 = er[e];
            short8 h0 = *(const short8*)(hin + (size_t)(r0.x & 0x1FFFF) * H + ch * 8);
            EACC(r0, h0)
        }
    }

    // write AggTile row nl: 4 bases x 16B, swizzled
    {
        char* row = lds + nl * 1024;
        const int swz = (nl & 7) << 4;
        uint4 pk;
#define PACK(A) pk.x = (unsigned)f2bf(A[0]) | ((unsigned)f2bf(A[1]) << 16); \
                pk.y = (unsigned)f2bf(A[2]) | ((unsigned)f2bf(A[3]) << 16); \
                pk.z = (unsigned)f2bf(A[4]) | ((unsigned)f2bf(A[5]) << 16); \
                pk.w = (unsigned)f2bf(A[6]) | ((unsigned)f2bf(A[7]) << 16);
        PACK(a0) *(uint4*)(row + ((0 * 256 + ch * 16) ^ swz)) = pk;
        PACK(a1) *(uint4*)(row + ((1 * 256 + ch * 16) ^ swz)) = pk;
        PACK(a2) *(uint4*)(row + ((2 * 256 + ch * 16) ^ swz)) = pk;
        PACK(a3) *(uint4*)(row + ((3 * 256 + ch * 16) ^ swz)) = pk;
#undef PACK
    }
    __syncthreads();

    // ---------------- phase B: [32 x 512] @ [512 x 128] ----------------
    const int wid  = tid >> 6;
    const int lane = tid & 63;
    const int n0 = wid * 16;           // this wave's 16 output cols
    const int lr = lane & 15;
    const int lg = lane >> 4;
    const char* bbase = (const char*)Wb + (size_t)(n0 + lr) * (NB * H) * 2;
    const int swz = (lr & 7) << 4;

    f32x4 acc0 = (f32x4){0.f, 0.f, 0.f, 0.f};
    f32x4 acc1 = (f32x4){0.f, 0.f, 0.f, 0.f};
#pragma unroll
    for (int ks = 0; ks < 16; ++ks) {
        const int kb = ks * 64 + lg * 16;
        short8 b   = *(const short8*)(bbase + kb);
        short8 av0 = *(const short8*)(lds + (lr)      * 1024 + (kb ^ swz));
        short8 av1 = *(const short8*)(lds + (16 + lr) * 1024 + (kb ^ swz));
        acc0 = __builtin_amdgcn_mfma_f32_16x16x32_bf16(av0, b, acc0, 0, 0, 0);
        acc1 = __builtin_amdgcn_mfma_f32_16x16x32_bf16(av1, b, acc1, 0, 0, 0);
    }

    const float bcol = bias[n0 + lr];
#pragma unroll
    for (int m = 0; m < 2; ++m) {
        const f32x4 a = m ? acc1 : acc0;
#pragma unroll
        for (int j = 0; j < 4; ++j) {
            const int rl   = m * 16 + lg * 4 + j;
            const int grow = v0 + rl;
            if (grow < M) {
                float val = fmaxf(a[j] + bcol, 0.f);
                if (write_bf16)
                    ((unsigned short*)outp)[(size_t)grow * H + n0 + lr] = f2bf(val);
                else
                    ((float*)outp)[(size_t)grow * H + n0 + lr] = val;
            }
        }
    }
}

extern "C" void kernel_launch(void* const* d_in, const int* in_sizes, int n_in,
                              void* d_out, int out_size, void* d_ws, size_t ws_size,
                              hipStream_t stream) {
    const float* feats  = (const float*)d_in[0];
    const int*   src    = (const int*)  d_in[1];
    const int*   dst    = (const int*)  d_in[2];
    const int*   etype  = (const int*)  d_in[3];
    const float* norm   = (const float*)d_in[4];
    const float* basis0 = (const float*)d_in[5];
    const float* comp0  = (const float*)d_in[6];
    const float* bias0  = (const float*)d_in[7];
    const float* basis1 = (const float*)d_in[8];
    const float* comp1  = (const float*)d_in[9];
    const float* bias1  = (const float*)d_in[10];
    float* out = (float*)d_out;

    const int M = in_sizes[0] / H;     // 50000
    const int E = in_sizes[1];         // 600000

    // workspace carve-up (256B aligned)
    char* ws = (char*)d_ws;
    size_t cur = 0;
    auto take = [&](size_t bytes) { void* p = ws + cur; cur += (bytes + 255) & ~(size_t)255; return p; };
    unsigned short* hbf  = (unsigned short*)take((size_t)M * H * 2);           // 12.8 MB
    unsigned short* h1bf = (unsigned short*)take((size_t)M * H * 2);           // 12.8 MB
    unsigned short* Wb   = (unsigned short*)take((size_t)2 * H * NB * H * 2);  // 256 KB
    int*   counts  = (int*)take((size_t)M * 4);
    int*   offs    = (int*)take((size_t)(M + 1) * 4);
    int*   partial = (int*)take((size_t)M * 4);
    int*   bsums   = (int*)take((size_t)64 * 4);
    int*   rank    = (int*)take((size_t)E * 4);
    uint2* er      = (uint2*)take((size_t)E * 8);                              // 4.8 MB

    dim3 blk(256);
    int eb  = (E + 255) / 256;
    int n4  = M * H / 4;
    int cb  = (n4 + 255) / 256;
    int mb  = (M + 255) / 256;
    int nsb = (M + 1023) / 1024;         // 49 <= 64
    int fb  = (M + DT - 1) / DT;         // 1563

    // ---- graph prep (stateless every call, single CSR build) ----
    hipMemsetAsync(counts, 0, (size_t)M * 4, stream);
    hist_rank    <<<eb, blk, 0, stream>>>(dst, counts, rank, E);
    scan_blocks  <<<nsb, 1024, 0, stream>>>(counts, partial, bsums, M);
    scan_carry   <<<1, 64, 0, stream>>>(bsums, nsb);
    scan_add     <<<mb, blk, 0, stream>>>(partial, bsums, offs, M);
    scatter_edges<<<eb, blk, 0, stream>>>(src, dst, etype, norm, offs, rank, er, E);
    convert_bf16 <<<cb, blk, 0, stream>>>(feats, hbf, n4);
    make_wb      <<<dim3(NB, H, 2), 128, 0, stream>>>(basis0, basis1, Wb);

    // ---- layer 0 ----
    fused_layer<<<fb, 512, 0, stream>>>(hbf, offs, er, comp0, Wb, bias0, h1bf, M, 1);
    // ---- layer 1 ----
    fused_layer<<<fb, 512, 0, stream>>>(h1bf, offs, er, comp1,
                                        Wb + (size_t)H * NB * H, bias1, out, M, 0);
}